// Round 4
// baseline (279.437 us; speedup 1.0000x reference)
//
#include <hip/hip_runtime.h>
#include <cstdint>

#define HEADS 16
#define DH 64
#define SEQ 2048
#define BATCH 4
#define DIM 1024
#define MTOT (BATCH*SEQ)   // 8192
#define NQKV (3*DIM)       // 3072

typedef short bf16x8 __attribute__((ext_vector_type(8)));
typedef float f32x4 __attribute__((ext_vector_type(4)));
typedef float f32x16 __attribute__((ext_vector_type(16)));

__device__ __forceinline__ unsigned short f2bf(float f) {
  union { float fv; unsigned int u; } c; c.fv = f;
  unsigned int u = c.u;
  u += 0x7FFFu + ((u >> 16) & 1u);   // round-to-nearest-even
  return (unsigned short)(u >> 16);
}

// pack two fp32 -> two bf16 (round-half-up) in one u32
__device__ __forceinline__ unsigned int pkbf(float lo, float hi) {
  union { float fv; unsigned int u; } a, b; a.fv = lo; b.fv = hi;
  return ((a.u + 0x8000u) >> 16) | ((b.u + 0x8000u) & 0xFFFF0000u);
}

__device__ __forceinline__ f32x4 mfma16(bf16x8 a, bf16x8 b, f32x4 c) {
  return __builtin_amdgcn_mfma_f32_16x16x32_bf16(a, b, c, 0, 0, 0);
}
__device__ __forceinline__ f32x16 mfma32(bf16x8 a, bf16x8 b, f32x16 c) {
  return __builtin_amdgcn_mfma_f32_32x32x16_bf16(a, b, c, 0, 0, 0);
}

typedef const __attribute__((address_space(1))) unsigned int* gas_ptr;
typedef __attribute__((address_space(3))) unsigned int* las_ptr;
__device__ __forceinline__ void gl2lds16(const void* g, void* l) {
  __builtin_amdgcn_global_load_lds((gas_ptr)g, (las_ptr)l, 16, 0, 0);
}

// Q pre-scale: Dh^-0.5 * log2(e)  (softmax done in exp2 domain)
#define QSCALE 0.18033688011112042f

// ---------------------------------------------------------------- cast x -> bf16
__global__ __launch_bounds__(256) void cast_f32_bf16(
    const float* __restrict__ in, unsigned short* __restrict__ out, int n4) {
  int i = blockIdx.x * blockDim.x + threadIdx.x;
  if (i >= n4) return;
  float4 v = reinterpret_cast<const float4*>(in)[i];
  uint2 o;
  o.x = (unsigned int)f2bf(v.x) | ((unsigned int)f2bf(v.y) << 16);
  o.y = (unsigned int)f2bf(v.z) | ((unsigned int)f2bf(v.w) << 16);
  reinterpret_cast<uint2*>(out)[i] = o;
}

// ------------------------------------------- transpose+cast: out[c][r] = in[r][c]
__global__ __launch_bounds__(256) void transpose_cast(
    const float* __restrict__ in, unsigned short* __restrict__ out, int R, int C) {
  __shared__ float tile[32][33];
  int c0 = blockIdx.x * 32, r0 = blockIdx.y * 32;
  int tx = threadIdx.x & 31, ty = threadIdx.x >> 5;  // ty 0..7
  for (int i = 0; i < 32; i += 8)
    tile[ty + i][tx] = in[(size_t)(r0 + ty + i) * C + c0 + tx];
  __syncthreads();
  for (int i = 0; i < 32; i += 8)
    out[(size_t)(c0 + ty + i) * R + r0 + tx] = f2bf(tile[tx][ty + i]);
}

// ------------------------------------------- V [b,h,n,d] -> Vt [b,h,d,n]
__global__ __launch_bounds__(256) void transpose_v(
    const unsigned short* __restrict__ V, unsigned short* __restrict__ Vt) {
  __shared__ unsigned short tile[64][72];
  int n0 = blockIdx.x * 64;
  size_t base = (size_t)blockIdx.y * SEQ * DH;
  int t = threadIdx.x;
  int r = t >> 2, c = (t & 3) * 8;
  *(uint4*)&tile[r][c]      = *(const uint4*)&V[base + (size_t)(n0 + r) * DH + c];
  *(uint4*)&tile[r][c + 32] = *(const uint4*)&V[base + (size_t)(n0 + r) * DH + c + 32];
  __syncthreads();
#pragma unroll
  for (int p = 0; p < 2; p++) {
    alignas(16) unsigned short tmp[8];
#pragma unroll
    for (int i = 0; i < 8; i++) tmp[i] = tile[c + p * 32 + i][r];
    *(uint4*)&Vt[base + (size_t)r * SEQ + n0 + c + p * 32] = *(uint4*)tmp;
  }
}

// ---------------------------------------------------------------- QKV GEMM
// m97 structure with BK=64 (halves barrier count: 32 -> 16 K-steps).
// LDT=64 shorts = 128B rows would be a 16-way read conflict, so the tile is
// stored with an XOR swizzle (T2/m173 both-sides pattern): gl2lds keeps a
// LINEAR dest while the GLOBAL source column is pre-swizzled
// (chunk ^ (row&7), row&7 == lane>>3); reads XOR the same term.
// Verified bank-uniform: 8 dword-accesses/bank per b128 wave read (minimum).
#define BM 128
#define BN 128
#define BK 64

__global__ __launch_bounds__(256) void gemm_qkv(
    const unsigned short* __restrict__ A, const unsigned short* __restrict__ Bt,
    unsigned short* __restrict__ Q, unsigned short* __restrict__ K,
    unsigned short* __restrict__ V) {
  __shared__ unsigned short sA[BM * BK];
  __shared__ unsigned short sB[BN * BK];
  const int KD = 1024;
  // XCD-bijective swizzle (nwg = 24*64 = 1536, %8==0)
  int gid = blockIdx.x + 24 * blockIdx.y;      // gridDim.x == 24
  int swz = (gid & 7) * 192 + (gid >> 3);      // cpx = 1536/8
  int m0 = (swz / 24) * BM;
  int n0 = (swz % 24) * BN;
  int t = threadIdx.x;
  int lane = t & 63, w = t >> 6;
  int wm = (w >> 1) * 64, wn = (w & 1) * 64;
  int fr = lane & 15, fg = lane >> 4;

  // staging: wave w, issue i covers rows i*32 + w*8 + (lane>>3);
  // global col chunk = (lane&7) ^ (lane>>3)  (pre-swizzled source)
  int srow = w * 8 + (lane >> 3);
  int scol = ((lane & 7) ^ (lane >> 3)) * 8;
  const unsigned short* gA = &A[(size_t)(m0 + srow) * KD + scol];
  const unsigned short* gB = &Bt[(size_t)(n0 + srow) * KD + scol];
  char* lA = (char*)sA + w * 1024;   // + i*4096 per issue; lane*16 implicit
  char* lB = (char*)sB + w * 1024;

  f32x4 acc[4][4];
#pragma unroll
  for (int i = 0; i < 4; i++)
#pragma unroll
    for (int j = 0; j < 4; j++) { f32x4 z = {0.f, 0.f, 0.f, 0.f}; acc[i][j] = z; }

  for (int k0 = 0; k0 < KD; k0 += BK) {
#pragma unroll
    for (int i = 0; i < 4; i++) {
      gl2lds16(gA + (size_t)i * 32 * KD + k0, lA + i * 4096);
      gl2lds16(gB + (size_t)i * 32 * KD + k0, lB + i * 4096);
    }
    __syncthreads();
#pragma unroll
    for (int ks = 0; ks < 2; ks++) {
      bf16x8 af[4], bfr[4];
#pragma unroll
      for (int mt = 0; mt < 4; mt++)
        af[mt] = *reinterpret_cast<const bf16x8*>(
            &sA[(wm + mt * 16 + fr) * BK + (((ks * 4 + fg) ^ (fr & 7)) * 8)]);
#pragma unroll
      for (int nt = 0; nt < 4; nt++)
        bfr[nt] = *reinterpret_cast<const bf16x8*>(
            &sB[(wn + nt * 16 + fr) * BK + (((ks * 4 + fg) ^ (fr & 7)) * 8)]);
#pragma unroll
      for (int mt = 0; mt < 4; mt++)
#pragma unroll
        for (int nt = 0; nt < 4; nt++)
          acc[mt][nt] = mfma16(af[mt], bfr[nt], acc[mt][nt]);
    }
    __syncthreads();
  }
  // epilogue: scatter to q/k/v [b][h][n][d]
  int rowq = (lane >> 4) * 4;
#pragma unroll
  for (int mt = 0; mt < 4; mt++)
#pragma unroll
    for (int nt = 0; nt < 4; nt++)
#pragma unroll
      for (int r = 0; r < 4; r++) {
        int m = m0 + wm + mt * 16 + rowq + r;
        int ncol = n0 + wn + nt * 16 + fr;
        int which = ncol >> 10;
        int hd = ncol & 1023;
        int b = m >> 11, nrow = m & 2047;
        float v = acc[mt][nt][r];
        if (which == 0) v *= QSCALE;  // Dh^-0.5 * log2e
        unsigned short* dst = (which == 0) ? Q : (which == 1 ? K : V);
        size_t idx = ((size_t)(b * HEADS + (hd >> 6)) * SEQ + nrow) * DH + (hd & 63);
        dst[idx] = f2bf(v);
      }
}

// ---------------------------------------------------------------- out-proj GEMM
__global__ __launch_bounds__(256) void gemm_out(
    const unsigned short* __restrict__ A, const unsigned short* __restrict__ Bt,
    const float* __restrict__ bias, float* __restrict__ C) {
  __shared__ unsigned short sA[BM * BK];
  __shared__ unsigned short sB[BN * BK];
  const int KD = 1024;
  // XCD-bijective swizzle (nwg = 8*64 = 512, %8==0)
  int gid = blockIdx.x + 8 * blockIdx.y;       // gridDim.x == 8
  int swz = (gid & 7) * 64 + (gid >> 3);       // cpx = 512/8
  int m0 = (swz / 8) * BM;
  int n0 = (swz % 8) * BN;
  int t = threadIdx.x;
  int lane = t & 63, w = t >> 6;
  int wm = (w >> 1) * 64, wn = (w & 1) * 64;
  int fr = lane & 15, fg = lane >> 4;

  int srow = w * 8 + (lane >> 3);
  int scol = ((lane & 7) ^ (lane >> 3)) * 8;
  const unsigned short* gA = &A[(size_t)(m0 + srow) * KD + scol];
  const unsigned short* gB = &Bt[(size_t)(n0 + srow) * KD + scol];
  char* lA = (char*)sA + w * 1024;
  char* lB = (char*)sB + w * 1024;

  f32x4 acc[4][4];
#pragma unroll
  for (int i = 0; i < 4; i++)
#pragma unroll
    for (int j = 0; j < 4; j++) { f32x4 z = {0.f, 0.f, 0.f, 0.f}; acc[i][j] = z; }

  for (int k0 = 0; k0 < KD; k0 += BK) {
#pragma unroll
    for (int i = 0; i < 4; i++) {
      gl2lds16(gA + (size_t)i * 32 * KD + k0, lA + i * 4096);
      gl2lds16(gB + (size_t)i * 32 * KD + k0, lB + i * 4096);
    }
    __syncthreads();
#pragma unroll
    for (int ks = 0; ks < 2; ks++) {
      bf16x8 af[4], bfr[4];
#pragma unroll
      for (int mt = 0; mt < 4; mt++)
        af[mt] = *reinterpret_cast<const bf16x8*>(
            &sA[(wm + mt * 16 + fr) * BK + (((ks * 4 + fg) ^ (fr & 7)) * 8)]);
#pragma unroll
      for (int nt = 0; nt < 4; nt++)
        bfr[nt] = *reinterpret_cast<const bf16x8*>(
            &sB[(wn + nt * 16 + fr) * BK + (((ks * 4 + fg) ^ (fr & 7)) * 8)]);
#pragma unroll
      for (int mt = 0; mt < 4; mt++)
#pragma unroll
        for (int nt = 0; nt < 4; nt++)
          acc[mt][nt] = mfma16(af[mt], bfr[nt], acc[mt][nt]);
    }
    __syncthreads();
  }
  int rowq = (lane >> 4) * 4;
#pragma unroll
  for (int mt = 0; mt < 4; mt++)
#pragma unroll
    for (int nt = 0; nt < 4; nt++)
#pragma unroll
      for (int r = 0; r < 4; r++) {
        int m = m0 + wm + mt * 16 + rowq + r;
        int ncol = n0 + wn + nt * 16 + fr;
        C[(size_t)m * DIM + ncol] = acc[mt][nt][r] + bias[ncol];
      }
}

// ---------------------------------------------------------------- flash attention
// ROUND-1 VERBATIM (proven 80.4 us, VGPR 64, single-buffer, 2 barriers/tile).
// grid (SEQ/128, HEADS, BATCH) via XCD-grouped gid remap; 4 waves x 32 q-rows.
#define LDA 68

__global__ __launch_bounds__(256, 4) void attention(
    const unsigned short* __restrict__ Qg, const unsigned short* __restrict__ Kg,
    const unsigned short* __restrict__ Vtg, unsigned short* __restrict__ Og) {
  __shared__ unsigned short smem[2 * 64 * 72];   // 18432 B; K/Vt use LDA=68, epilogue needs full 18432
  unsigned short* sK  = smem;
  unsigned short* sVt = smem + 64 * LDA;

  // XCD-grouping swizzle: all 16 q-blocks of one (h,b) land on one XCD (gid%8
  // heuristic) -> per-XCD L2 holds only 8 heads' K/Vt (hot set ~256KB << 4MB).
  int gid = blockIdx.x + 16 * (blockIdx.y + 16 * blockIdx.z);  // 0..1023
  int qb   = (gid >> 3) & 15;
  int pair = ((gid & 7) << 3) | (gid >> 7);   // xcd*8 + group
  int h = pair & 15, b = pair >> 4;

  size_t base = (size_t)(b * HEADS + h) * SEQ * DH;
  const unsigned short* Q = Qg + base;
  const unsigned short* K = Kg + base;
  const unsigned short* Vt = Vtg + base;
  int t = threadIdx.x, lane = t & 63, w = t >> 6;
  int m = lane & 31, kh = lane >> 5;
  int q0 = qb * 128 + w * 32;

  // Q frags for this wave's 32 rows (B-operand of S^T), held all kernel
  bf16x8 qf[4];
#pragma unroll
  for (int kt = 0; kt < 4; kt++)
    qf[kt] = *reinterpret_cast<const bf16x8*>(
        &Q[(size_t)(q0 + m) * DH + kt * 16 + kh * 8]);

  f32x16 oaccT[2];   // [dhalf], C layout: row=d', col=qrow
#pragma unroll
  for (int dh = 0; dh < 2; dh++)
#pragma unroll
    for (int i = 0; i < 16; i++) oaccT[dh][i] = 0.f;
  float rs = 0.f;

  int sr = t >> 2, sc = (t & 3) * 8;

  for (int j0 = 0; j0 < SEQ; j0 += 64) {
    // stage K [j][d] and Vt [d][j]; rows are 136B so write as b64 pairs
    {
      uint4 a0 = *(const uint4*)&K[(size_t)(j0 + sr) * DH + sc];
      uint4 a1 = *(const uint4*)&K[(size_t)(j0 + sr) * DH + sc + 32];
      uint4 b0 = *(const uint4*)&Vt[(size_t)sr * SEQ + j0 + sc];
      uint4 b1 = *(const uint4*)&Vt[(size_t)sr * SEQ + j0 + sc + 32];
      unsigned short* pk0 = &sK[sr * LDA + sc];
      unsigned short* pk1 = &sK[sr * LDA + sc + 32];
      unsigned short* pv0 = &sVt[sr * LDA + sc];
      unsigned short* pv1 = &sVt[sr * LDA + sc + 32];
      *(uint2*)pk0       = make_uint2(a0.x, a0.y);
      *(uint2*)(pk0 + 4) = make_uint2(a0.z, a0.w);
      *(uint2*)pk1       = make_uint2(a1.x, a1.y);
      *(uint2*)(pk1 + 4) = make_uint2(a1.z, a1.w);
      *(uint2*)pv0       = make_uint2(b0.x, b0.y);
      *(uint2*)(pv0 + 4) = make_uint2(b0.z, b0.w);
      *(uint2*)pv1       = make_uint2(b1.x, b1.y);
      *(uint2*)(pv1 + 4) = make_uint2(b1.z, b1.w);
    }
    __syncthreads();

    // S^T = K.Q^T, exp2, pack P into registers (pp[s'][p]: j = 4kh+8s'+2p+{0,1})
    unsigned int pp[8][2];
#pragma unroll
    for (int jt = 0; jt < 2; jt++) {
      bf16x8 kf[4];
#pragma unroll
      for (int kt = 0; kt < 4; kt++) {
        union { uint2 u[2]; bf16x8 v; } kc;
        const unsigned short* p = &sK[(jt * 32 + m) * LDA + (2 * kt + kh) * 8];
        kc.u[0] = *(const uint2*)p;
        kc.u[1] = *(const uint2*)(p + 4);
        kf[kt] = kc.v;
      }
      f32x16 s;
#pragma unroll
      for (int i = 0; i < 16; i++) s[i] = 0.f;
#pragma unroll
      for (int kt = 0; kt < 4; kt++)
        s = mfma32(kf[kt], qf[kt], s);
      float e[16];
#pragma unroll
      for (int i = 0; i < 16; i++) e[i] = __builtin_amdgcn_exp2f(s[i]);
      // rowsum partial (lane holds 32 of 64 j's per tile; partner has rest)
      float t0 = (e[0] + e[1]) + (e[2] + e[3]);
      float t1 = (e[4] + e[5]) + (e[6] + e[7]);
      float t2 = (e[8] + e[9]) + (e[10] + e[11]);
      float t3 = (e[12] + e[13]) + (e[14] + e[15]);
      rs += (t0 + t1) + (t2 + t3);
#pragma unroll
      for (int sl = 0; sl < 4; sl++) {
        pp[4 * jt + sl][0] = pkbf(e[4 * sl + 0], e[4 * sl + 1]);
        pp[4 * jt + sl][1] = pkbf(e[4 * sl + 2], e[4 * sl + 3]);
      }
    }

    // O^T += Vt(pi) @ P^T : A-frag = two b64 Vt reads, B-frag = pp registers
#pragma unroll
    for (int kb = 0; kb < 4; kb++) {
#pragma unroll
      for (int dh = 0; dh < 2; dh++) {
        union { uint2 u[2]; bf16x8 v; } ac;
        const unsigned short* p = &sVt[(32 * dh + m) * LDA + 16 * kb + 4 * kh];
        ac.u[0] = *(const uint2*)p;
        ac.u[1] = *(const uint2*)(p + 8);
        union { unsigned int u[4]; bf16x8 v; } bc;
        bc.u[0] = pp[2 * kb][0];
        bc.u[1] = pp[2 * kb][1];
        bc.u[2] = pp[2 * kb + 1][0];
        bc.u[3] = pp[2 * kb + 1][1];
        oaccT[dh] = mfma32(ac.v, bc.v, oaccT[dh]);
      }
    }
    __syncthreads();
  }

  // complete rowsum (other 32 j's live in the partner half-wave)
  float inv;
  {
    float tot = rs + __shfl_xor(rs, 32);
    inv = 1.0f / tot;
  }

  // epilogue: normalize, transpose O^T -> O via per-wave LDS (stride 36 dwords),
  // then coalesced uint4 global stores. smem reused: wave w gets 4608 B.
  unsigned int* ew = (unsigned int*)smem + (size_t)w * 32 * 36;
#pragma unroll
  for (int dh = 0; dh < 2; dh++)
#pragma unroll
    for (int sl = 0; sl < 4; sl++) {
      unsigned int u0 = pkbf(oaccT[dh][4 * sl + 0] * inv, oaccT[dh][4 * sl + 1] * inv);
      unsigned int u1 = pkbf(oaccT[dh][4 * sl + 2] * inv, oaccT[dh][4 * sl + 3] * inv);
      uint2 pk; pk.x = u0; pk.y = u1;
      // d = 32dh + 8sl + 4kh + {0..3} -> uint idx = 16dh + 4sl + 2kh
      *(uint2*)&ew[m * 36 + 16 * dh + 4 * sl + 2 * kh] = pk;
    }
  // wave-private region: lgkmcnt ordering within wave suffices (no barrier)
  {
    int mr = lane >> 3, ch = lane & 7;
#pragma unroll
    for (int it = 0; it < 4; it++) {
      uint4 vv = *(const uint4*)&ew[(8 * it + mr) * 36 + ch * 4];
      int n = q0 + 8 * it + mr;
      *(uint4*)&Og[((size_t)(b * SEQ + n)) * DIM + h * DH + ch * 8] = vv;
    }
  }
}

// ---------------------------------------------------------------- launch
extern "C" void kernel_launch(void* const* d_in, const int* in_sizes, int n_in,
                              void* d_out, int out_size, void* d_ws, size_t ws_size,
                              hipStream_t stream) {
  const float* x     = (const float*)d_in[0];  // [4,2048,1024]
  const float* w_qkv = (const float*)d_in[1];  // [1024,3072]
  const float* w_out = (const float*)d_in[2];  // [1024,1024]
  const float* b_out = (const float*)d_in[3];  // [1024]
  float* out = (float*)d_out;                  // [4,2048,1024]

  char* ws = (char*)d_ws;
  unsigned short* xb     = (unsigned short*)ws; ws += (size_t)MTOT * DIM * 2;
  unsigned short* wqkv_t = (unsigned short*)ws; ws += (size_t)NQKV * DIM * 2;
  unsigned short* wout_t = (unsigned short*)ws; ws += (size_t)DIM * DIM * 2;
  unsigned short* qb_    = (unsigned short*)ws; ws += (size_t)BATCH * HEADS * SEQ * DH * 2;
  unsigned short* kb_    = (unsigned short*)ws; ws += (size_t)BATCH * HEADS * SEQ * DH * 2;
  unsigned short* vb_    = (unsigned short*)ws; ws += (size_t)BATCH * HEADS * SEQ * DH * 2;
  unsigned short* attnb  = (unsigned short*)ws; ws += (size_t)MTOT * DIM * 2;
  unsigned short* vt_    = xb;  // alias: xb dead after gemm_qkv, same size (16.8MB)

  // 1. casts / transposes
  cast_f32_bf16<<<(MTOT * DIM / 4 + 255) / 256, 256, 0, stream>>>(x, xb, MTOT * DIM / 4);
  transpose_cast<<<dim3(NQKV / 32, DIM / 32), 256, 0, stream>>>(w_qkv, wqkv_t, DIM, NQKV);
  transpose_cast<<<dim3(DIM / 32, DIM / 32), 256, 0, stream>>>(w_out, wout_t, DIM, DIM);

  // 2. QKV projection (scatters to q/k/v [b][h][n][d], scales Q by Dh^-0.5*log2e)
  gemm_qkv<<<dim3(NQKV / BN, MTOT / BM), 256, 0, stream>>>(xb, wqkv_t, qb_, kb_, vb_);

  // 3. V -> V^T  [b,h,d,n]   (xb is dead now; vt_ aliases it)
  transpose_v<<<dim3(SEQ / 64, BATCH * HEADS), 256, 0, stream>>>(vb_, vt_);

  // 4. flash attention (register-resident P, round-1 proven structure)
  attention<<<dim3(SEQ / 128, HEADS, BATCH), 256, 0, stream>>>(qb_, kb_, vt_, attnb);

  // 5. output projection + bias
  gemm_out<<<dim3(DIM / BN, MTOT / BM), 256, 0, stream>>>(attnb, wout_t, b_out, out);
}

// Round 5
// 265.021 us; speedup vs baseline: 1.0544x; 1.0544x over previous
//
#include <hip/hip_runtime.h>
#include <cstdint>

#define HEADS 16
#define DH 64
#define SEQ 2048
#define BATCH 4
#define DIM 1024
#define MTOT (BATCH*SEQ)   // 8192
#define NQKV (3*DIM)       // 3072

typedef short bf16x8 __attribute__((ext_vector_type(8)));
typedef float f32x4 __attribute__((ext_vector_type(4)));
typedef float f32x16 __attribute__((ext_vector_type(16)));

__device__ __forceinline__ unsigned short f2bf(float f) {
  union { float fv; unsigned int u; } c; c.fv = f;
  unsigned int u = c.u;
  u += 0x7FFFu + ((u >> 16) & 1u);   // round-to-nearest-even
  return (unsigned short)(u >> 16);
}

// pack two fp32 -> two bf16 in one u32 via HW instruction (1 VALU op vs ~5)
// PROVEN: r1-vs-r4 A/B on attention = 11 us (cvtpk vs manual pack)
__device__ __forceinline__ unsigned int cvtpk(float lo, float hi) {
  unsigned int r;
  asm("v_cvt_pk_bf16_f32 %0, %1, %2" : "=v"(r) : "v"(lo), "v"(hi));
  return r;
}

__device__ __forceinline__ f32x4 mfma16(bf16x8 a, bf16x8 b, f32x4 c) {
  return __builtin_amdgcn_mfma_f32_16x16x32_bf16(a, b, c, 0, 0, 0);
}
__device__ __forceinline__ f32x16 mfma32(bf16x8 a, bf16x8 b, f32x16 c) {
  return __builtin_amdgcn_mfma_f32_32x32x16_bf16(a, b, c, 0, 0, 0);
}

typedef const __attribute__((address_space(1))) unsigned int* gas_ptr;
typedef __attribute__((address_space(3))) unsigned int* las_ptr;
__device__ __forceinline__ void gl2lds16(const void* g, void* l) {
  __builtin_amdgcn_global_load_lds((gas_ptr)g, (las_ptr)l, 16, 0, 0);
}

// Q pre-scale: Dh^-0.5 * log2(e)  (softmax done in exp2 domain)
#define QSCALE 0.18033688011112042f

// ---------------------------------------------------------------- cast x -> bf16
__global__ __launch_bounds__(256) void cast_f32_bf16(
    const float* __restrict__ in, unsigned short* __restrict__ out, int n4) {
  int i = blockIdx.x * blockDim.x + threadIdx.x;
  if (i >= n4) return;
  float4 v = reinterpret_cast<const float4*>(in)[i];
  uint2 o;
  o.x = (unsigned int)f2bf(v.x) | ((unsigned int)f2bf(v.y) << 16);
  o.y = (unsigned int)f2bf(v.z) | ((unsigned int)f2bf(v.w) << 16);
  reinterpret_cast<uint2*>(out)[i] = o;
}

// ------------------------------------------- transpose+cast: out[c][r] = in[r][c]
__global__ __launch_bounds__(256) void transpose_cast(
    const float* __restrict__ in, unsigned short* __restrict__ out, int R, int C) {
  __shared__ float tile[32][33];
  int c0 = blockIdx.x * 32, r0 = blockIdx.y * 32;
  int tx = threadIdx.x & 31, ty = threadIdx.x >> 5;  // ty 0..7
  for (int i = 0; i < 32; i += 8)
    tile[ty + i][tx] = in[(size_t)(r0 + ty + i) * C + c0 + tx];
  __syncthreads();
  for (int i = 0; i < 32; i += 8)
    out[(size_t)(c0 + ty + i) * R + r0 + tx] = f2bf(tile[tx][ty + i]);
}

// ------------------------------------------- V [b,h,n,d] -> Vt [b,h,d,n]
__global__ __launch_bounds__(256) void transpose_v(
    const unsigned short* __restrict__ V, unsigned short* __restrict__ Vt) {
  __shared__ unsigned short tile[64][72];
  int n0 = blockIdx.x * 64;
  size_t base = (size_t)blockIdx.y * SEQ * DH;
  int t = threadIdx.x;
  int r = t >> 2, c = (t & 3) * 8;
  *(uint4*)&tile[r][c]      = *(const uint4*)&V[base + (size_t)(n0 + r) * DH + c];
  *(uint4*)&tile[r][c + 32] = *(const uint4*)&V[base + (size_t)(n0 + r) * DH + c + 32];
  __syncthreads();
#pragma unroll
  for (int p = 0; p < 2; p++) {
    alignas(16) unsigned short tmp[8];
#pragma unroll
    for (int i = 0; i < 8; i++) tmp[i] = tile[c + p * 32 + i][r];
    *(uint4*)&Vt[base + (size_t)r * SEQ + n0 + c + p * 32] = *(uint4*)tmp;
  }
}

// ---------------------------------------------------------------- QKV GEMM
// m97 structure, BK=64, XOR-swizzled tiles (both-sides pattern, r4-proven).
// Round-5: epilogue rewritten — all idx math hoisted (b / which / hh / dcol
// are wave-uniform or per-nt consts; verified no 16-alignment boundary
// crossings), f2bf -> cvtpk+hi/lo, QSCALE as uniform branch. Epilogue was
// ~half the kernel's instructions at K=1024 (only 16 K-steps to amortize).
#define BM 128
#define BN 128
#define BK 64

__global__ __launch_bounds__(256) void gemm_qkv(
    const unsigned short* __restrict__ A, const unsigned short* __restrict__ Bt,
    unsigned short* __restrict__ Q, unsigned short* __restrict__ K,
    unsigned short* __restrict__ V) {
  __shared__ unsigned short sA[BM * BK];
  __shared__ unsigned short sB[BN * BK];
  const int KD = 1024;
  // XCD-bijective swizzle (nwg = 24*64 = 1536, %8==0)
  int gid = blockIdx.x + 24 * blockIdx.y;      // gridDim.x == 24
  int swz = (gid & 7) * 192 + (gid >> 3);      // cpx = 1536/8
  int m0 = (swz / 24) * BM;
  int n0 = (swz % 24) * BN;
  int t = threadIdx.x;
  int lane = t & 63, w = t >> 6;
  int wm = (w >> 1) * 64, wn = (w & 1) * 64;
  int fr = lane & 15, fg = lane >> 4;

  // staging: wave w, issue i covers rows i*32 + w*8 + (lane>>3);
  // global col chunk = (lane&7) ^ (lane>>3)  (pre-swizzled source)
  int srow = w * 8 + (lane >> 3);
  int scol = ((lane & 7) ^ (lane >> 3)) * 8;
  const unsigned short* gA = &A[(size_t)(m0 + srow) * KD + scol];
  const unsigned short* gB = &Bt[(size_t)(n0 + srow) * KD + scol];
  char* lA = (char*)sA + w * 1024;   // + i*4096 per issue; lane*16 implicit
  char* lB = (char*)sB + w * 1024;

  f32x4 acc[4][4];
#pragma unroll
  for (int i = 0; i < 4; i++)
#pragma unroll
    for (int j = 0; j < 4; j++) { f32x4 z = {0.f, 0.f, 0.f, 0.f}; acc[i][j] = z; }

  for (int k0 = 0; k0 < KD; k0 += BK) {
#pragma unroll
    for (int i = 0; i < 4; i++) {
      gl2lds16(gA + (size_t)i * 32 * KD + k0, lA + i * 4096);
      gl2lds16(gB + (size_t)i * 32 * KD + k0, lB + i * 4096);
    }
    __syncthreads();
#pragma unroll
    for (int ks = 0; ks < 2; ks++) {
      bf16x8 af[4], bfr[4];
#pragma unroll
      for (int mt = 0; mt < 4; mt++)
        af[mt] = *reinterpret_cast<const bf16x8*>(
            &sA[(wm + mt * 16 + fr) * BK + (((ks * 4 + fg) ^ (fr & 7)) * 8)]);
#pragma unroll
      for (int nt = 0; nt < 4; nt++)
        bfr[nt] = *reinterpret_cast<const bf16x8*>(
            &sB[(wn + nt * 16 + fr) * BK + (((ks * 4 + fg) ^ (fr & 7)) * 8)]);
#pragma unroll
      for (int mt = 0; mt < 4; mt++)
#pragma unroll
        for (int nt = 0; nt < 4; nt++)
          acc[mt][nt] = mfma16(af[mt], bfr[nt], acc[mt][nt]);
    }
    __syncthreads();
  }

  // epilogue: scatter to q/k/v [b][h][n][d] — hoisted addressing
  int rowq = (lane >> 4) * 4;
  int b = m0 >> 11;                       // block-uniform (BM=128 | 2048)
  int nrow0 = (m0 & 2047) + wm + rowq;    // + mt*16 + r, no wrap within block
#pragma unroll
  for (int nt = 0; nt < 4; nt++) {
    int ncb = n0 + wn + nt * 16;          // lane-uniform column base
    int which = ncb >> 10;                // uniform: fr<16 can't cross 1024
    int hdb = ncb & 1023;
    int hh = hdb >> 6;                    // uniform: hdb%64<=48, +fr<=63
    int dcol = (hdb & 63) + fr;
    unsigned short* dst = (which == 0) ? Q : (which == 1 ? K : V);
    size_t cbase = ((size_t)(b * HEADS + hh) * SEQ) * DH + dcol;
#pragma unroll
    for (int mt = 0; mt < 4; mt++) {
      f32x4 av = acc[mt][nt];
      if (which == 0) {                   // uniform branch (Q pre-scale)
        av[0] *= QSCALE; av[1] *= QSCALE; av[2] *= QSCALE; av[3] *= QSCALE;
      }
      size_t idx = cbase + (size_t)(nrow0 + mt * 16) * DH;
      unsigned int u0 = cvtpk(av[0], av[1]);
      unsigned int u1 = cvtpk(av[2], av[3]);
      dst[idx]          = (unsigned short)u0;
      dst[idx + DH]     = (unsigned short)(u0 >> 16);
      dst[idx + 2 * DH] = (unsigned short)u1;
      dst[idx + 3 * DH] = (unsigned short)(u1 >> 16);
    }
  }
}

// ---------------------------------------------------------------- out-proj GEMM
__global__ __launch_bounds__(256) void gemm_out(
    const unsigned short* __restrict__ A, const unsigned short* __restrict__ Bt,
    const float* __restrict__ bias, float* __restrict__ C) {
  __shared__ unsigned short sA[BM * BK];
  __shared__ unsigned short sB[BN * BK];
  const int KD = 1024;
  // XCD-bijective swizzle (nwg = 8*64 = 512, %8==0)
  int gid = blockIdx.x + 8 * blockIdx.y;       // gridDim.x == 8
  int swz = (gid & 7) * 64 + (gid >> 3);       // cpx = 512/8
  int m0 = (swz / 8) * BM;
  int n0 = (swz % 8) * BN;
  int t = threadIdx.x;
  int lane = t & 63, w = t >> 6;
  int wm = (w >> 1) * 64, wn = (w & 1) * 64;
  int fr = lane & 15, fg = lane >> 4;

  int srow = w * 8 + (lane >> 3);
  int scol = ((lane & 7) ^ (lane >> 3)) * 8;
  const unsigned short* gA = &A[(size_t)(m0 + srow) * KD + scol];
  const unsigned short* gB = &Bt[(size_t)(n0 + srow) * KD + scol];
  char* lA = (char*)sA + w * 1024;
  char* lB = (char*)sB + w * 1024;

  f32x4 acc[4][4];
#pragma unroll
  for (int i = 0; i < 4; i++)
#pragma unroll
    for (int j = 0; j < 4; j++) { f32x4 z = {0.f, 0.f, 0.f, 0.f}; acc[i][j] = z; }

  for (int k0 = 0; k0 < KD; k0 += BK) {
#pragma unroll
    for (int i = 0; i < 4; i++) {
      gl2lds16(gA + (size_t)i * 32 * KD + k0, lA + i * 4096);
      gl2lds16(gB + (size_t)i * 32 * KD + k0, lB + i * 4096);
    }
    __syncthreads();
#pragma unroll
    for (int ks = 0; ks < 2; ks++) {
      bf16x8 af[4], bfr[4];
#pragma unroll
      for (int mt = 0; mt < 4; mt++)
        af[mt] = *reinterpret_cast<const bf16x8*>(
            &sA[(wm + mt * 16 + fr) * BK + (((ks * 4 + fg) ^ (fr & 7)) * 8)]);
#pragma unroll
      for (int nt = 0; nt < 4; nt++)
        bfr[nt] = *reinterpret_cast<const bf16x8*>(
            &sB[(wn + nt * 16 + fr) * BK + (((ks * 4 + fg) ^ (fr & 7)) * 8)]);
#pragma unroll
      for (int mt = 0; mt < 4; mt++)
#pragma unroll
        for (int nt = 0; nt < 4; nt++)
          acc[mt][nt] = mfma16(af[mt], bfr[nt], acc[mt][nt]);
    }
    __syncthreads();
  }

  // epilogue: hoisted addressing; bias loaded once per nt
  int rowq = (lane >> 4) * 4;
#pragma unroll
  for (int nt = 0; nt < 4; nt++) {
    int ncol = n0 + wn + nt * 16 + fr;
    float bb = bias[ncol];
    size_t cb = (size_t)(m0 + wm + rowq) * DIM + ncol;
#pragma unroll
    for (int mt = 0; mt < 4; mt++)
#pragma unroll
      for (int r = 0; r < 4; r++)
        C[cb + (size_t)(mt * 16 + r) * DIM] = acc[mt][nt][r] + bb;
  }
}

// ---------------------------------------------------------------- flash attention
// ROUND-1 EXACT (proven 80.4 us): cvtpk packing, single-buffer, 2 barriers/tile.
// grid (SEQ/128, HEADS, BATCH) via XCD-grouped gid remap; 4 waves x 32 q-rows.
#define LDA 68

__global__ __launch_bounds__(256, 4) void attention(
    const unsigned short* __restrict__ Qg, const unsigned short* __restrict__ Kg,
    const unsigned short* __restrict__ Vtg, unsigned short* __restrict__ Og) {
  __shared__ unsigned short smem[2 * 64 * 72];   // 18432 B; K/Vt use LDA=68, epilogue needs full 18432
  unsigned short* sK  = smem;
  unsigned short* sVt = smem + 64 * LDA;

  // XCD-grouping swizzle: all 16 q-blocks of one (h,b) land on one XCD (gid%8
  // heuristic) -> per-XCD L2 holds only 8 heads' K/Vt (hot set ~256KB << 4MB).
  int gid = blockIdx.x + 16 * (blockIdx.y + 16 * blockIdx.z);  // 0..1023
  int qb   = (gid >> 3) & 15;
  int pair = ((gid & 7) << 3) | (gid >> 7);   // xcd*8 + group
  int h = pair & 15, b = pair >> 4;

  size_t base = (size_t)(b * HEADS + h) * SEQ * DH;
  const unsigned short* Q = Qg + base;
  const unsigned short* K = Kg + base;
  const unsigned short* Vt = Vtg + base;
  int t = threadIdx.x, lane = t & 63, w = t >> 6;
  int m = lane & 31, kh = lane >> 5;
  int q0 = qb * 128 + w * 32;

  // Q frags for this wave's 32 rows (B-operand of S^T), held all kernel
  bf16x8 qf[4];
#pragma unroll
  for (int kt = 0; kt < 4; kt++)
    qf[kt] = *reinterpret_cast<const bf16x8*>(
        &Q[(size_t)(q0 + m) * DH + kt * 16 + kh * 8]);

  f32x16 oaccT[2];   // [dhalf], C layout: row=d', col=qrow
#pragma unroll
  for (int dh = 0; dh < 2; dh++)
#pragma unroll
    for (int i = 0; i < 16; i++) oaccT[dh][i] = 0.f;
  float rs = 0.f;

  int sr = t >> 2, sc = (t & 3) * 8;

  for (int j0 = 0; j0 < SEQ; j0 += 64) {
    // stage K [j][d] and Vt [d][j]; rows are 136B so write as b64 pairs
    {
      uint4 a0 = *(const uint4*)&K[(size_t)(j0 + sr) * DH + sc];
      uint4 a1 = *(const uint4*)&K[(size_t)(j0 + sr) * DH + sc + 32];
      uint4 b0 = *(const uint4*)&Vt[(size_t)sr * SEQ + j0 + sc];
      uint4 b1 = *(const uint4*)&Vt[(size_t)sr * SEQ + j0 + sc + 32];
      unsigned short* pk0 = &sK[sr * LDA + sc];
      unsigned short* pk1 = &sK[sr * LDA + sc + 32];
      unsigned short* pv0 = &sVt[sr * LDA + sc];
      unsigned short* pv1 = &sVt[sr * LDA + sc + 32];
      *(uint2*)pk0       = make_uint2(a0.x, a0.y);
      *(uint2*)(pk0 + 4) = make_uint2(a0.z, a0.w);
      *(uint2*)pk1       = make_uint2(a1.x, a1.y);
      *(uint2*)(pk1 + 4) = make_uint2(a1.z, a1.w);
      *(uint2*)pv0       = make_uint2(b0.x, b0.y);
      *(uint2*)(pv0 + 4) = make_uint2(b0.z, b0.w);
      *(uint2*)pv1       = make_uint2(b1.x, b1.y);
      *(uint2*)(pv1 + 4) = make_uint2(b1.z, b1.w);
    }
    __syncthreads();

    // S^T = K.Q^T, exp2, pack P into registers (pp[s'][p]: j = 4kh+8s'+2p+{0,1})
    unsigned int pp[8][2];
#pragma unroll
    for (int jt = 0; jt < 2; jt++) {
      bf16x8 kf[4];
#pragma unroll
      for (int kt = 0; kt < 4; kt++) {
        union { uint2 u[2]; bf16x8 v; } kc;
        const unsigned short* p = &sK[(jt * 32 + m) * LDA + (2 * kt + kh) * 8];
        kc.u[0] = *(const uint2*)p;
        kc.u[1] = *(const uint2*)(p + 4);
        kf[kt] = kc.v;
      }
      f32x16 s;
#pragma unroll
      for (int i = 0; i < 16; i++) s[i] = 0.f;
#pragma unroll
      for (int kt = 0; kt < 4; kt++)
        s = mfma32(kf[kt], qf[kt], s);
      float e[16];
#pragma unroll
      for (int i = 0; i < 16; i++) e[i] = __builtin_amdgcn_exp2f(s[i]);
      // rowsum partial (lane holds 32 of 64 j's per tile; partner has rest)
      float t0 = (e[0] + e[1]) + (e[2] + e[3]);
      float t1 = (e[4] + e[5]) + (e[6] + e[7]);
      float t2 = (e[8] + e[9]) + (e[10] + e[11]);
      float t3 = (e[12] + e[13]) + (e[14] + e[15]);
      rs += (t0 + t1) + (t2 + t3);
#pragma unroll
      for (int sl = 0; sl < 4; sl++) {
        pp[4 * jt + sl][0] = cvtpk(e[4 * sl + 0], e[4 * sl + 1]);
        pp[4 * jt + sl][1] = cvtpk(e[4 * sl + 2], e[4 * sl + 3]);
      }
    }

    // O^T += Vt(pi) @ P^T : A-frag = two b64 Vt reads, B-frag = pp registers
#pragma unroll
    for (int kb = 0; kb < 4; kb++) {
#pragma unroll
      for (int dh = 0; dh < 2; dh++) {
        union { uint2 u[2]; bf16x8 v; } ac;
        const unsigned short* p = &sVt[(32 * dh + m) * LDA + 16 * kb + 4 * kh];
        ac.u[0] = *(const uint2*)p;
        ac.u[1] = *(const uint2*)(p + 8);
        union { unsigned int u[4]; bf16x8 v; } bc;
        bc.u[0] = pp[2 * kb][0];
        bc.u[1] = pp[2 * kb][1];
        bc.u[2] = pp[2 * kb + 1][0];
        bc.u[3] = pp[2 * kb + 1][1];
        oaccT[dh] = mfma32(ac.v, bc.v, oaccT[dh]);
      }
    }
    __syncthreads();
  }

  // complete rowsum (other 32 j's live in the partner half-wave)
  float inv;
  {
    float tot = rs + __shfl_xor(rs, 32);
    inv = 1.0f / tot;
  }

  // epilogue: normalize, transpose O^T -> O via per-wave LDS (stride 36 dwords),
  // then coalesced uint4 global stores. smem reused: wave w gets 4608 B.
  unsigned int* ew = (unsigned int*)smem + (size_t)w * 32 * 36;
#pragma unroll
  for (int dh = 0; dh < 2; dh++)
#pragma unroll
    for (int sl = 0; sl < 4; sl++) {
      unsigned int u0 = cvtpk(oaccT[dh][4 * sl + 0] * inv, oaccT[dh][4 * sl + 1] * inv);
      unsigned int u1 = cvtpk(oaccT[dh][4 * sl + 2] * inv, oaccT[dh][4 * sl + 3] * inv);
      uint2 pk; pk.x = u0; pk.y = u1;
      // d = 32dh + 8sl + 4kh + {0..3} -> uint idx = 16dh + 4sl + 2kh
      *(uint2*)&ew[m * 36 + 16 * dh + 4 * sl + 2 * kh] = pk;
    }
  // wave-private region: lgkmcnt ordering within wave suffices (no barrier)
  {
    int mr = lane >> 3, ch = lane & 7;
#pragma unroll
    for (int it = 0; it < 4; it++) {
      uint4 vv = *(const uint4*)&ew[(8 * it + mr) * 36 + ch * 4];
      int n = q0 + 8 * it + mr;
      *(uint4*)&Og[((size_t)(b * SEQ + n)) * DIM + h * DH + ch * 8] = vv;
    }
  }
}

// ---------------------------------------------------------------- launch
extern "C" void kernel_launch(void* const* d_in, const int* in_sizes, int n_in,
                              void* d_out, int out_size, void* d_ws, size_t ws_size,
                              hipStream_t stream) {
  const float* x     = (const float*)d_in[0];  // [4,2048,1024]
  const float* w_qkv = (const float*)d_in[1];  // [1024,3072]
  const float* w_out = (const float*)d_in[2];  // [1024,1024]
  const float* b_out = (const float*)d_in[3];  // [1024]
  float* out = (float*)d_out;                  // [4,2048,1024]

  char* ws = (char*)d_ws;
  unsigned short* xb     = (unsigned short*)ws; ws += (size_t)MTOT * DIM * 2;
  unsigned short* wqkv_t = (unsigned short*)ws; ws += (size_t)NQKV * DIM * 2;
  unsigned short* wout_t = (unsigned short*)ws; ws += (size_t)DIM * DIM * 2;
  unsigned short* qb_    = (unsigned short*)ws; ws += (size_t)BATCH * HEADS * SEQ * DH * 2;
  unsigned short* kb_    = (unsigned short*)ws; ws += (size_t)BATCH * HEADS * SEQ * DH * 2;
  unsigned short* vb_    = (unsigned short*)ws; ws += (size_t)BATCH * HEADS * SEQ * DH * 2;
  unsigned short* attnb  = (unsigned short*)ws; ws += (size_t)MTOT * DIM * 2;
  unsigned short* vt_    = xb;  // alias: xb dead after gemm_qkv, same size (16.8MB)

  // 1. casts / transposes
  cast_f32_bf16<<<(MTOT * DIM / 4 + 255) / 256, 256, 0, stream>>>(x, xb, MTOT * DIM / 4);
  transpose_cast<<<dim3(NQKV / 32, DIM / 32), 256, 0, stream>>>(w_qkv, wqkv_t, DIM, NQKV);
  transpose_cast<<<dim3(DIM / 32, DIM / 32), 256, 0, stream>>>(w_out, wout_t, DIM, DIM);

  // 2. QKV projection (scatters to q/k/v [b][h][n][d], scales Q by Dh^-0.5*log2e)
  gemm_qkv<<<dim3(NQKV / BN, MTOT / BM), 256, 0, stream>>>(xb, wqkv_t, qb_, kb_, vb_);

  // 3. V -> V^T  [b,h,d,n]   (xb is dead now; vt_ aliases it)
  transpose_v<<<dim3(SEQ / 64, BATCH * HEADS), 256, 0, stream>>>(vb_, vt_);

  // 4. flash attention (register-resident P, round-1 proven structure)
  attention<<<dim3(SEQ / 128, HEADS, BATCH), 256, 0, stream>>>(qb_, kb_, vt_, attnb);

  // 5. output projection + bias
  gemm_out<<<dim3(DIM / BN, MTOT / BM), 256, 0, stream>>>(attnb, wout_t, b_out, out);
}